// Round 16
// baseline (315.310 us; speedup 1.0000x reference)
//
#include <hip/hip_runtime.h>
#include <hip/hip_bf16.h>
#include <math.h>

#define NN 24576
#define NE 98304
#define ETOT (NE + NN)
#define NG 512
#define NB 512
#define LL 1000
#define TL 124
#define NTILE 9
#define PROT_BLKS (NB * NTILE)
#define CNT_BLKS (ETOT / 256)
#define AS1_BLKS (NN * 2 / 256)

typedef __attribute__((ext_vector_type(8))) short short8;
typedef __attribute__((ext_vector_type(4))) short short4v;
typedef __attribute__((ext_vector_type(4))) float f32x4;

__device__ inline short f2bf(float x) {
    union { __hip_bfloat16 b; short s; } u;
    u.b = __float2bfloat16(x);
    return u.s;
}

__device__ inline float bf2f(short s) {
    return __uint_as_float(((unsigned)(unsigned short)s) << 16);
}

__device__ inline void atomicMaxFloat(float* addr, float val) {
    int* ai = (int*)addr;
    int old = __float_as_int(*addr);
    while (__int_as_float(old) < val) {
        int assumed = old;
        old = atomicCAS(ai, assumed, __float_as_int(val));
        if (old == assumed) break;
    }
}

// ---------------- D1: init + weight prep (disjoint block ranges) ----------------
__global__ void k_init_prep(int* deg, int* cursor, float* sums, float* cnt, float* pmax,
                            const float* K1, const float* K2, const float* W2, const float* Pe,
                            const float* W1, const float* as1c, const float* ad1c,
                            const float* as2c, const float* ad2c,
                            short* Bswz1, short* Bswz2, short* Bh2, short* Bl2, short* Peb,
                            float* wvec) {
    int bid = blockIdx.x, t = threadIdx.x;
    if (bid < 256) {                       // init body
        int i = bid * 256 + t;
        if (i < NN) { deg[i] = 0; cursor[i] = 0; }
        if (i < NG * 128) sums[i] = 0.f;
        if (i < NG) cnt[i] = 0.f;
        if (i < NB * 128) pmax[i] = -1e30f;
        return;
    }
    int idx = (bid - 256) * 256 + t;       // prep body (160 blocks)
    if (idx < 22 * 64) Peb[idx] = f2bf(Pe[idx]);
    if (idx < 20) {             // was1 [0..9], wad1 [10..19]
        int q = idx % 10, hd = q / 5, f = q % 5;
        const float* av = (idx < 10) ? as1c : ad1c;
        float s = 0.f;
        for (int c = 0; c < 64; c++) s += W1[f * 128 + hd * 64 + c] * av[hd * 64 + c];
        wvec[idx < 10 ? q : 10 + q] = s;
    }
    if (idx >= 32 && idx < 288) {   // wa_s2 [32..159], wa_d2 [160..287]
        int q = idx - 32;
        int kk = q & 127;
        const float* av = (q < 128) ? as2c : ad2c;
        float s = 0.f;
        for (int n2 = 0; n2 < 128; n2++) s += W2[kk * 128 + n2] * av[n2];
        wvec[idx] = s;
    }
    if (idx < 192 * 64) {       // B1
        int j = idx & 7, lane = (idx >> 3) & 63, rest = idx >> 9;
        int nt = rest & 3, kb = rest >> 2;
        int k = kb * 32 + ((lane >> 4) << 3) + j;
        int n = nt * 16 + (lane & 15);
        int kk = k >> 6, i = k & 63;
        Bswz1[idx] = f2bf(K1[n * 192 + i * 3 + kk]);
    }
    if (idx < 320 * 128) {      // B2
        int j = idx & 7, lane = (idx >> 3) & 63, rest = idx >> 9;
        int nt = rest & 7, kb = rest >> 3;
        int k = kb * 32 + ((lane >> 4) << 3) + j;
        int n = nt * 16 + (lane & 15);
        int kk = k / 64, i = k % 64;
        Bswz2[idx] = f2bf(K2[n * 320 + i * 5 + kk]);
    }
    if (idx < 128 * 128) {      // W2 hi/lo
        int j = idx & 7, lane = (idx >> 3) & 63, rest = idx >> 9;
        int nt = rest & 7, kb = rest >> 3;
        int k = kb * 32 + ((lane >> 4) << 3) + j;
        int n = nt * 16 + (lane & 15);
        float v = W2[k * 128 + n];
        short hh = f2bf(v);
        Bh2[idx] = hh;
        Bl2[idx] = f2bf(v - bf2f(hh));
    }
}

// ---------------- D2: protein + CSR count + as1 (disjoint ranges; R11/R13/R15-verified) ----------------
#define SSTR 72
__global__ __launch_bounds__(256, 4) void k_prot_cnt_as1(
    const int* seq, const short* Peb, const short* Bswz1, const float* bk1,
    const short* Bswz2, const float* bk2, float* pmax,
    const int* ei, int* deg,
    const float* x, const float* wvec, float* as1o, float* ad1o) {
    int bid = blockIdx.x;
    int t = threadIdx.x;

    if (bid >= PROT_BLKS) {
        int rb = bid - PROT_BLKS;
        if (rb < CNT_BLKS) {               // CSR count
            int e = rb * 256 + t;
            int d = (e < NE) ? ei[NE + e] : e - NE;
            atomicAdd(&deg[d], 1);
        } else {                           // as1: per-node attention scalars
            int idx = (rb - CNT_BLKS) * 256 + t;   // NN*2
            int n = idx >> 1, hd = idx & 1;
            float s = 0.f, dv = 0.f;
#pragma unroll
            for (int f = 0; f < 5; f++) {
                float xv = x[n * 5 + f];
                s += xv * wvec[hd * 5 + f];
                dv += xv * wvec[10 + hd * 5 + f];
            }
            as1o[idx] = s;
            ad1o[idx] = dv;
        }
        return;
    }

    // ---- protein body (R10-verified) ----
    __shared__ __align__(16) short sEmb[130 * SSTR];
    __shared__ __align__(16) short s1[132 * SSTR];

    int b = bid / NTILE;
    int tile = bid - b * NTILE;
    int t0 = tile * TL;
    int wv = t >> 6, lane = t & 63;
    int ln15 = lane & 15, quad = lane >> 4;
    int mhalf = wv & 1, nhalf = wv >> 1;

    for (int j0 = 0; j0 < 130; j0 += 64) {
        int j = j0 + (t >> 2);
        if (j < 130) {
            int c0 = (t & 3) * 16;
            int l = t0 - 3 + j;
            int id = (l >= 0 && l < LL) ? seq[b * LL + l] : -1;
            short* dst = &sEmb[j * SSTR + c0];
            if (id >= 0) {
                const short8* src = (const short8*)&Peb[id * 64 + c0];
                *(short8*)dst = src[0];
                *(short8*)(dst + 8) = src[1];
            } else {
                *(short8*)dst = (short8){0, 0, 0, 0, 0, 0, 0, 0};
                *(short8*)(dst + 8) = (short8){0, 0, 0, 0, 0, 0, 0, 0};
            }
        }
    }
    s1[(128 + (t >> 6)) * SSTR + (t & 63)] = 0;
    __syncthreads();

    {   // conv1: wave = 4 mt x 2 nt
        f32x4 acc[4][2];
#pragma unroll
        for (int mi = 0; mi < 4; mi++)
#pragma unroll
            for (int ni = 0; ni < 2; ni++) acc[mi][ni] = (f32x4){0.f, 0.f, 0.f, 0.f};
#pragma unroll
        for (int kb = 0; kb < 6; kb++) {
            int koff = kb * 32 + quad * 8;
            int kk = koff >> 6, i0 = koff & 63;
            short8 b0 = *(const short8*)&Bswz1[((kb * 4 + nhalf * 2 + 0) * 64 + lane) * 8];
            short8 b1 = *(const short8*)&Bswz1[((kb * 4 + nhalf * 2 + 1) * 64 + lane) * 8];
#pragma unroll
            for (int mi = 0; mi < 4; mi++) {
                int arow = (mhalf * 4 + mi) * 16 + ln15 + kk;
                short8 a = *(const short8*)&sEmb[arow * SSTR + i0];
                acc[mi][0] = __builtin_amdgcn_mfma_f32_16x16x32_bf16(a, b0, acc[mi][0], 0, 0, 0);
                acc[mi][1] = __builtin_amdgcn_mfma_f32_16x16x32_bf16(a, b1, acc[mi][1], 0, 0, 0);
            }
        }
#pragma unroll
        for (int mi = 0; mi < 4; mi++) {
            int mt = mhalf * 4 + mi;
#pragma unroll
            for (int ni = 0; ni < 2; ni++) {
                int col = (nhalf * 2 + ni) * 16 + ln15;
                float bias = bk1[col];
#pragma unroll
                for (int r = 0; r < 4; r++) {
                    int q = mt * 16 + quad * 4 + r;
                    int l = t0 - 2 + q;
                    float v = acc[mi][ni][r] + bias;
                    v = v > 0.f ? v : __expf(v) - 1.f;
                    s1[q * SSTR + col] = (l >= 0 && l < LL) ? f2bf(v) : (short)0;
                }
            }
        }
    }
    __syncthreads();

    // conv2: wave = 4 mt x 4 nt; B from global (L2); barrier-free K-loop
    f32x4 acc2[4][4];
#pragma unroll
    for (int mi = 0; mi < 4; mi++)
#pragma unroll
        for (int ni = 0; ni < 4; ni++) acc2[mi][ni] = (f32x4){0.f, 0.f, 0.f, 0.f};
#pragma unroll 2
    for (int kb = 0; kb < 10; kb++) {
        int koff = kb * 32 + quad * 8;
        int kk = koff >> 6, i0 = koff & 63;
        short8 a[4], bb[4];
#pragma unroll
        for (int mi = 0; mi < 4; mi++) {
            int arow = (mhalf * 4 + mi) * 16 + ln15 + kk;
            a[mi] = *(const short8*)&s1[arow * SSTR + i0];
        }
#pragma unroll
        for (int ni = 0; ni < 4; ni++)
            bb[ni] = *(const short8*)&Bswz2[((kb * 8 + nhalf * 4 + ni) * 64 + lane) * 8];
#pragma unroll
        for (int mi = 0; mi < 4; mi++)
#pragma unroll
            for (int ni = 0; ni < 4; ni++)
                acc2[mi][ni] = __builtin_amdgcn_mfma_f32_16x16x32_bf16(a[mi], bb[ni], acc2[mi][ni], 0, 0, 0);
    }

    // epilogue: masked max over raw acc, then bias+elu once (elu monotonic)
#pragma unroll
    for (int ni = 0; ni < 4; ni++) {
        int col = (nhalf * 4 + ni) * 16 + ln15;
        float mx = -1e30f;
#pragma unroll
        for (int mi = 0; mi < 4; mi++) {
#pragma unroll
            for (int r = 0; r < 4; r++) {
                int p = (mhalf * 4 + mi) * 16 + quad * 4 + r;
                if (p < TL && t0 + p < LL) mx = fmaxf(mx, acc2[mi][ni][r]);
            }
        }
        mx = fmaxf(mx, __shfl_xor(mx, 16, 64));
        mx = fmaxf(mx, __shfl_xor(mx, 32, 64));
        if (quad == 0) {
            float v = mx + bk2[col];
            v = v > 0.f ? v : __expf(v) - 1.f;
            atomicMaxFloat(&pmax[b * 128 + col], v);
        }
    }
}

// ---------------- D3: rowptr (one dispatch, R12-verified) + batch-cnt (disjoint blocks) ----------------
__global__ void k_rowptr_cnt(const int* deg, int* rowptr, const int* batch, float* cnt) {
    int bid = blockIdx.x, t = threadIdx.x;
    if (bid >= NN / 256) {                  // cnt body: 96 blocks
        int n = (bid - NN / 256) * 256 + t;
        atomicAdd(&cnt[batch[n]], 1.f);
        return;
    }
    __shared__ int s[256];
    __shared__ int red[4];
    int b = bid, i = b * 256 + t;
    int v = deg[i];
    s[t] = v;
    __syncthreads();
    for (int o = 1; o < 256; o <<= 1) {
        int xx = (t >= o) ? s[t - o] : 0;
        __syncthreads();
        s[t] += xx;
        __syncthreads();
    }
    int excl = s[t] - v;
    int psum = 0;
    for (int k = t; k < b * 256; k += 256) psum += deg[k];
    for (int off = 32; off > 0; off >>= 1) psum += __shfl_down(psum, off, 64);
    if ((t & 63) == 0) red[t >> 6] = psum;
    __syncthreads();
    int pref = red[0] + red[1] + red[2] + red[3];
    rowptr[i] = excl + pref;
    if (i == 0) rowptr[NN] = ETOT;
}

__global__ void k_scatter(const int* ei, const int* rowptr, int* cursor, int* colidx) {
    int e = blockIdx.x * 256 + threadIdx.x;
    if (e >= ETOT) return;
    int s, d;
    if (e < NE) { s = ei[e]; d = ei[NE + e]; }
    else { s = d = e - NE; }
    int pos = atomicAdd(&cursor[d], 1);
    colidx[rowptr[d] + pos] = s;
}

// ---------------- GAT layer 1: x-space aggregation + fused W1 (no max-shift) ----------------
__global__ void k_agg2x(const int* rowptr, const int* colidx, const float* x,
                        const float* as_, const float* ad_,
                        const float* W1, const float* b1, const float* wvec,
                        unsigned int* g1b, float* as2, float* ad2) {
    __shared__ float sW[640];
    __shared__ float sb1[128];
    __shared__ float swa[256];
    int t = threadIdx.x;
    for (int i = t; i < 640; i += 256) sW[i] = W1[i];
    if (t < 128) { sb1[t] = b1[t]; swa[t] = wvec[32 + t]; swa[128 + t] = wvec[160 + t]; }
    __syncthreads();

    int d = blockIdx.x * 16 + (t >> 4);   // grid = NN/16
    int g = t & 15;
    int hd = (g < 5) ? 0 : 1;
    int f = (g < 5) ? g : g - 5;
    float adv = ad_[d * 2 + hd];
    int p0 = rowptr[d], p1 = rowptr[d + 1];
    float den = 0.f, acc = 0.f;
    if (g < 10) {
        for (int pc = p0; pc < p1; pc += 4) {
            int sarr[4]; float ev[4], xv[4];
#pragma unroll
            for (int i = 0; i < 4; i++) {
                int pp = pc + i;
                sarr[i] = colidx[pp < p1 ? pp : p1 - 1];
            }
#pragma unroll
            for (int i = 0; i < 4; i++) {
                ev[i] = as_[sarr[i] * 2 + hd];
                xv[i] = x[sarr[i] * 5 + f];
            }
#pragma unroll
            for (int i = 0; i < 4; i++) {
                if (pc + i < p1) {
                    float e = ev[i] + adv;
                    e = e >= 0.f ? e : 0.2f * e;
                    float w = __expf(e);
                    den += w;
                    acc += w * xv[i];
                }
            }
        }
    }
    float xn = acc / (den + 1e-16f);
    int gb = (t & 63) & ~15;
    int hcol = g >> 3;
    float xs[5];
#pragma unroll
    for (int f2 = 0; f2 < 5; f2++)
        xs[f2] = __shfl(xn, gb + hcol * 5 + f2, 64);
    float ps = 0.f, pd = 0.f;
    float g1v[8];
#pragma unroll
    for (int k = 0; k < 8; k++) {
        int col = g * 8 + k;
        float v = sb1[col];
#pragma unroll
        for (int f2 = 0; f2 < 5; f2++) v += xs[f2] * sW[f2 * 128 + col];
        v = v > 0.f ? v : __expf(v) - 1.f;
        g1v[k] = v;
        ps += v * swa[col];
        pd += v * swa[128 + col];
    }
    uint4 pk;
    pk.x = ((unsigned)(unsigned short)f2bf(g1v[1]) << 16) | (unsigned)(unsigned short)f2bf(g1v[0]);
    pk.y = ((unsigned)(unsigned short)f2bf(g1v[3]) << 16) | (unsigned)(unsigned short)f2bf(g1v[2]);
    pk.z = ((unsigned)(unsigned short)f2bf(g1v[5]) << 16) | (unsigned)(unsigned short)f2bf(g1v[4]);
    pk.w = ((unsigned)(unsigned short)f2bf(g1v[7]) << 16) | (unsigned)(unsigned short)f2bf(g1v[6]);
    *(uint4*)&g1b[d * 64 + g * 4] = pk;
#pragma unroll
    for (int msk = 1; msk < 16; msk <<= 1) {
        ps += __shfl_xor(ps, msk, 64);
        pd += __shfl_xor(pd, msk, 64);
    }
    if (g == 0) { as2[d] = ps; ad2[d] = pd; }
}

// ---------------- GAT layer 2 aggregation in g1-space (packed bf16; no max-shift) ----------------
__global__ void k_agg1y(const int* rowptr, const int* colidx, const unsigned int* hb,
                        const float* as_, const float* ad_, float* yacc) {
    int t = threadIdx.x;
    int d = blockIdx.x * 4 + (t >> 6);   // wave per node
    int c = t & 63;
    float adv = ad_[d];
    int p0 = rowptr[d], p1 = rowptr[d + 1];
    float den = 0.f, acc0 = 0.f, acc1 = 0.f;
    for (int pc = p0; pc < p1; pc += 4) {
        int sarr[4]; float ev[4]; unsigned int hv[4];
#pragma unroll
        for (int i = 0; i < 4; i++) {
            int pp = pc + i;
            sarr[i] = colidx[pp < p1 ? pp : p1 - 1];
        }
#pragma unroll
        for (int i = 0; i < 4; i++) {
            ev[i] = as_[sarr[i]];
            hv[i] = hb[sarr[i] * 64 + c];
        }
#pragma unroll
        for (int i = 0; i < 4; i++) {
            if (pc + i < p1) {
                float e = ev[i] + adv;
                e = e >= 0.f ? e : 0.2f * e;
                float w = __expf(e);
                den += w;
                acc0 += w * __uint_as_float(hv[i] << 16);
                acc1 += w * __uint_as_float(hv[i] & 0xFFFF0000u);
            }
        }
    }
    float inv = 1.f / (den + 1e-16f);
    ((float2*)yacc)[d * 64 + c] = (float2){acc0 * inv, acc1 * inv};
}

// ---------------- D7: W2 matmul + fused mean-pool atomics (split-bf16 MFMA) ----------------
#define ASTR 136
__global__ __launch_bounds__(256, 2) void k_g2mm_pool(
    const float* yacc, const short* Bh, const short* Bl, const float* b2,
    const int* batch, float* sums) {
    __shared__ __align__(16) short Ah[64 * ASTR];
    __shared__ __align__(16) short Al[64 * ASTR];
    int t = threadIdx.x;
    int m0 = blockIdx.x * 64;
    int wv = t >> 6, lane = t & 63;
    int ln15 = lane & 15, quad = lane >> 4;

    for (int i = t; i < 64 * 32; i += 256) {
        int row = i >> 5, c4 = (i & 31) * 4;
        float4 v = *(const float4*)&yacc[(m0 + row) * 128 + c4];
        short4v hi, lo;
        hi.x = f2bf(v.x); lo.x = f2bf(v.x - bf2f(hi.x));
        hi.y = f2bf(v.y); lo.y = f2bf(v.y - bf2f(hi.y));
        hi.z = f2bf(v.z); lo.z = f2bf(v.z - bf2f(hi.z));
        hi.w = f2bf(v.w); lo.w = f2bf(v.w - bf2f(hi.w));
        *(short4v*)&Ah[row * ASTR + c4] = hi;
        *(short4v*)&Al[row * ASTR + c4] = lo;
    }
    __syncthreads();

    f32x4 acc[8];
#pragma unroll
    for (int nt = 0; nt < 8; nt++) acc[nt] = (f32x4){0.f, 0.f, 0.f, 0.f};
    int arow = wv * 16 + ln15;
#pragma unroll
    for (int kb = 0; kb < 4; kb++) {
        int koff = kb * 32 + quad * 8;
        short8 a_hi = *(const short8*)&Ah[arow * ASTR + koff];
        short8 a_lo = *(const short8*)&Al[arow * ASTR + koff];
#pragma unroll
        for (int nt = 0; nt < 8; nt++) {
            short8 bh = *(const short8*)&Bh[((kb * 8 + nt) * 64 + lane) * 8];
            short8 bl = *(const short8*)&Bl[((kb * 8 + nt) * 64 + lane) * 8];
            acc[nt] = __builtin_amdgcn_mfma_f32_16x16x32_bf16(a_hi, bh, acc[nt], 0, 0, 0);
            acc[nt] = __builtin_amdgcn_mfma_f32_16x16x32_bf16(a_hi, bl, acc[nt], 0, 0, 0);
            acc[nt] = __builtin_amdgcn_mfma_f32_16x16x32_bf16(a_lo, bh, acc[nt], 0, 0, 0);
        }
    }

    // epilogue: bias+elu, run-length atomic mean-pool (batch sorted; 4 consecutive rows/lane)
    int nbase = m0 + wv * 16 + quad * 4;
    int bg[4];
#pragma unroll
    for (int r = 0; r < 4; r++) bg[r] = batch[nbase + r];
#pragma unroll
    for (int nt = 0; nt < 8; nt++) {
        int col = nt * 16 + ln15;
        float bias = b2[col];
        float vv[4];
#pragma unroll
        for (int r = 0; r < 4; r++) {
            float v = acc[nt][r] + bias;
            vv[r] = v > 0.f ? v : __expf(v) - 1.f;
        }
        int cur = bg[0];
        float a = vv[0];
#pragma unroll
        for (int r = 1; r < 4; r++) {
            if (bg[r] == cur) a += vv[r];
            else {
                atomicAdd(&sums[cur * 128 + col], a);
                cur = bg[r];
                a = vv[r];
            }
        }
        atomicAdd(&sums[cur * 128 + col], a);
    }
}

// ---------------- tail v2: 512 thr, concurrent prot/drug, K-split f1/f2 (R15-verified) ----------------
__global__ __launch_bounds__(512) void k_tail(
    const float* pmax, const float* Wp, const float* bp,
    const float* sums, const float* cnt, const float* Wd, const float* bd,
    const float* Wf1, const float* bf1, const float* Wf2, const float* bf2,
    const float* Wo, const float* bo, float* out) {
    __shared__ float in2[512];
    __shared__ float part1[512];
    __shared__ float hh[128];
    __shared__ float part2[512];
    __shared__ float h2s[64];
    int g = blockIdx.x, t = threadIdx.x;

    if (t < 256) {
        float pacc = bp[t];
#pragma unroll 8
        for (int i = 0; i < 128; i++) pacc += pmax[g * 128 + i] * Wp[i * 256 + t];
        in2[256 + t] = pacc > 0.f ? pacc : 0.f;
    } else {
        int o = t - 256;
        float c = cnt[g]; c = c < 1.f ? 1.f : c;
        float inv = 1.f / c;
        float dacc = bd[o];
#pragma unroll 8
        for (int i = 0; i < 128; i++) dacc += sums[g * 128 + i] * inv * Wd[i * 256 + o];
        in2[o] = dacc > 0.f ? dacc : 0.f;
    }
    __syncthreads();

    {
        int o = t >> 2, ks = t & 3;
        float p = 0.f;
        int c0 = ks * 128;
#pragma unroll 8
        for (int cc = c0; cc < c0 + 128; cc++) p += in2[cc] * Wf1[cc * 128 + o];
        part1[t] = p;
    }
    __syncthreads();
    if (t < 128) {
        float a = bf1[t] + part1[t * 4] + part1[t * 4 + 1] + part1[t * 4 + 2] + part1[t * 4 + 3];
        hh[t] = a > 0.f ? a : 0.f;
    }
    __syncthreads();

    {
        int o = t >> 3, ks = t & 7;
        float p = 0.f;
        int c0 = ks * 16;
#pragma unroll
        for (int cc = c0; cc < c0 + 16; cc++) p += hh[cc] * Wf2[cc * 64 + o];
        part2[t] = p;
    }
    __syncthreads();
    if (t < 64) {
        float a = bf2[t];
#pragma unroll
        for (int k = 0; k < 8; k++) a += part2[t * 8 + k];
        h2s[t] = a > 0.f ? a : 0.f;
    }
    __syncthreads();

    if (t < 64) {
        float p = h2s[t] * Wo[t];
#pragma unroll
        for (int off = 32; off > 0; off >>= 1) p += __shfl_down(p, off, 64);
        if (t == 0) out[g] = p + bo[0];
    }
}

extern "C" void kernel_launch(void* const* d_in, const int* in_sizes, int n_in,
                              void* d_out, int out_size, void* d_ws, size_t ws_size,
                              hipStream_t stream) {
    (void)in_sizes; (void)n_in; (void)out_size; (void)ws_size;
    const float* x   = (const float*)d_in[0];
    const int* ei    = (const int*)d_in[1];
    const int* batch = (const int*)d_in[2];
    const int* seq   = (const int*)d_in[3];
    const float* W1  = (const float*)d_in[4];
    const float* a_s1 = (const float*)d_in[5];
    const float* a_d1 = (const float*)d_in[6];
    const float* b1  = (const float*)d_in[7];
    const float* W2  = (const float*)d_in[8];
    const float* a_s2 = (const float*)d_in[9];
    const float* a_d2 = (const float*)d_in[10];
    const float* b2  = (const float*)d_in[11];
    const float* Wd  = (const float*)d_in[12];
    const float* bd  = (const float*)d_in[13];
    const float* Pe  = (const float*)d_in[14];
    const float* K1  = (const float*)d_in[15];
    const float* bk1 = (const float*)d_in[16];
    const float* K2  = (const float*)d_in[17];
    const float* bk2 = (const float*)d_in[18];
    const float* Wp  = (const float*)d_in[19];
    const float* bp  = (const float*)d_in[20];
    const float* Wf1 = (const float*)d_in[21];
    const float* bf1 = (const float*)d_in[22];
    const float* Wf2 = (const float*)d_in[23];
    const float* bf2 = (const float*)d_in[24];
    const float* Wo  = (const float*)d_in[25];
    const float* bo  = (const float*)d_in[26];
    float* out = (float*)d_out;

    float* w = (float*)d_ws;
    float* g1bf = w; w += NN * 64;    // packed-bf16 uint[NN*64]
    float* yacc = w; w += NN * 128;
    float* as1  = w; w += NN * 2;
    float* ad1  = w; w += NN * 2;
    float* as2  = w; w += NN;
    float* ad2  = w; w += NN;
    float* sums = w; w += NG * 128;
    float* cnt  = w; w += NG;
    float* pmax = w; w += NB * 128;
    float* wvec = w; w += 512;
    short* Bswz1 = (short*)w; w += 192 * 64 / 2;
    short* Bswz2 = (short*)w; w += 320 * 128 / 2;
    short* Bh2  = (short*)w; w += 128 * 128 / 2;
    short* Bl2  = (short*)w; w += 128 * 128 / 2;
    short* Peb  = (short*)w; w += 22 * 64 / 2 + 8;
    int* deg    = (int*)w; w += NN;
    int* cursor = (int*)w; w += NN;
    int* rowptr = (int*)w; w += NN + 8;
    int* colidx = (int*)w; w += ETOT;

    unsigned int* g1b = (unsigned int*)g1bf;

    // D1: init + weight prep
    hipLaunchKernelGGL(k_init_prep, dim3(256 + 160), dim3(256), 0, stream,
                       deg, cursor, sums, cnt, pmax,
                       K1, K2, W2, Pe, W1, a_s1, a_d1, a_s2, a_d2,
                       Bswz1, Bswz2, Bh2, Bl2, Peb, wvec);

    // D2: protein + CSR count + as1
    hipLaunchKernelGGL(k_prot_cnt_as1, dim3(PROT_BLKS + CNT_BLKS + AS1_BLKS), dim3(256), 0, stream,
                       seq, Peb, Bswz1, bk1, Bswz2, bk2, pmax,
                       ei, deg, x, wvec, as1, ad1);

    // D3: rowptr + batch-cnt
    hipLaunchKernelGGL(k_rowptr_cnt, dim3(NN / 256 + NN / 256), dim3(256), 0, stream,
                       deg, rowptr, batch, cnt);

    // D4: scatter
    hipLaunchKernelGGL(k_scatter, dim3(ETOT / 256), dim3(256), 0, stream, ei, rowptr, cursor, colidx);

    // D5: GAT layer 1 aggregation (x-space) + fused W1
    hipLaunchKernelGGL(k_agg2x, dim3(NN / 16), dim3(256), 0, stream,
                       rowptr, colidx, x, as1, ad1, W1, b1, wvec, g1b, as2, ad2);

    // D6: GAT layer 2 aggregation
    hipLaunchKernelGGL(k_agg1y, dim3(NN / 4), dim3(256), 0, stream,
                       rowptr, colidx, g1b, as2, ad2, yacc);

    // D7: W2 matmul + fused mean-pool
    hipLaunchKernelGGL(k_g2mm_pool, dim3(NN / 64), dim3(256), 0, stream,
                       yacc, Bh2, Bl2, b2, batch, sums);

    // D8: tail v2
    hipLaunchKernelGGL(k_tail, dim3(NG), dim3(512), 0, stream,
                       pmax, Wp, bp, sums, cnt, Wd, bd, Wf1, bf1, Wf2, bf2, Wo, bo, out);
}

// Round 17
// 309.630 us; speedup vs baseline: 1.0183x; 1.0183x over previous
//
#include <hip/hip_runtime.h>
#include <hip/hip_bf16.h>
#include <math.h>

#define NN 24576
#define NE 98304
#define ETOT (NE + NN)
#define NG 512
#define NB 512
#define LL 1000
#define TL 124
#define NTILE 9
#define PROT_BLKS (NB * NTILE)
#define CNT_BLKS (ETOT / 256)
#define AS1_BLKS (NN * 2 / 256)

typedef __attribute__((ext_vector_type(8))) short short8;
typedef __attribute__((ext_vector_type(4))) short short4v;
typedef __attribute__((ext_vector_type(4))) float f32x4;

__device__ inline short f2bf(float x) {
    union { __hip_bfloat16 b; short s; } u;
    u.b = __float2bfloat16(x);
    return u.s;
}

__device__ inline float bf2f(short s) {
    return __uint_as_float(((unsigned)(unsigned short)s) << 16);
}

__device__ inline void atomicMaxFloat(float* addr, float val) {
    int* ai = (int*)addr;
    int old = __float_as_int(*addr);
    while (__int_as_float(old) < val) {
        int assumed = old;
        old = atomicCAS(ai, assumed, __float_as_int(val));
        if (old == assumed) break;
    }
}

// ---------------- D1: init + weight prep (disjoint block ranges) ----------------
__global__ void k_init_prep(int* deg, int* cursor, float* sums, float* cnt, float* pmax,
                            const float* K1, const float* K2, const float* W2, const float* Pe,
                            const float* W1, const float* as1c, const float* ad1c,
                            const float* as2c, const float* ad2c,
                            short* Bswz1, short* Bswz2, short* Bh2, short* Bl2, short* Peb,
                            float* wvec) {
    int bid = blockIdx.x, t = threadIdx.x;
    if (bid < 256) {                       // init body
        int i = bid * 256 + t;
        if (i < NN) { deg[i] = 0; cursor[i] = 0; }
        if (i < NG * 128) sums[i] = 0.f;
        if (i < NG) cnt[i] = 0.f;
        if (i < NB * 128) pmax[i] = -1e30f;
        return;
    }
    int idx = (bid - 256) * 256 + t;       // prep body (160 blocks)
    if (idx < 22 * 64) Peb[idx] = f2bf(Pe[idx]);
    if (idx < 20) {             // was1 [0..9], wad1 [10..19]
        int q = idx % 10, hd = q / 5, f = q % 5;
        const float* av = (idx < 10) ? as1c : ad1c;
        float s = 0.f;
        for (int c = 0; c < 64; c++) s += W1[f * 128 + hd * 64 + c] * av[hd * 64 + c];
        wvec[idx < 10 ? q : 10 + q] = s;
    }
    if (idx >= 32 && idx < 288) {   // wa_s2 [32..159], wa_d2 [160..287]
        int q = idx - 32;
        int kk = q & 127;
        const float* av = (q < 128) ? as2c : ad2c;
        float s = 0.f;
        for (int n2 = 0; n2 < 128; n2++) s += W2[kk * 128 + n2] * av[n2];
        wvec[idx] = s;
    }
    if (idx < 192 * 64) {       // B1
        int j = idx & 7, lane = (idx >> 3) & 63, rest = idx >> 9;
        int nt = rest & 3, kb = rest >> 2;
        int k = kb * 32 + ((lane >> 4) << 3) + j;
        int n = nt * 16 + (lane & 15);
        int kk = k >> 6, i = k & 63;
        Bswz1[idx] = f2bf(K1[n * 192 + i * 3 + kk]);
    }
    if (idx < 320 * 128) {      // B2
        int j = idx & 7, lane = (idx >> 3) & 63, rest = idx >> 9;
        int nt = rest & 7, kb = rest >> 3;
        int k = kb * 32 + ((lane >> 4) << 3) + j;
        int n = nt * 16 + (lane & 15);
        int kk = k / 64, i = k % 64;
        Bswz2[idx] = f2bf(K2[n * 320 + i * 5 + kk]);
    }
    if (idx < 128 * 128) {      // W2 hi/lo
        int j = idx & 7, lane = (idx >> 3) & 63, rest = idx >> 9;
        int nt = rest & 7, kb = rest >> 3;
        int k = kb * 32 + ((lane >> 4) << 3) + j;
        int n = nt * 16 + (lane & 15);
        float v = W2[k * 128 + n];
        short hh = f2bf(v);
        Bh2[idx] = hh;
        Bl2[idx] = f2bf(v - bf2f(hh));
    }
}

// ---------------- D2: protein + CSR count + as1 (disjoint ranges; R11/R13/R15-verified) ----------------
#define SSTR 72
__global__ __launch_bounds__(256, 4) void k_prot_cnt_as1(
    const int* seq, const short* Peb, const short* Bswz1, const float* bk1,
    const short* Bswz2, const float* bk2, float* pmax,
    const int* ei, int* deg,
    const float* x, const float* wvec, float* as1o, float* ad1o) {
    int bid = blockIdx.x;
    int t = threadIdx.x;

    if (bid >= PROT_BLKS) {
        int rb = bid - PROT_BLKS;
        if (rb < CNT_BLKS) {               // CSR count
            int e = rb * 256 + t;
            int d = (e < NE) ? ei[NE + e] : e - NE;
            atomicAdd(&deg[d], 1);
        } else {                           // as1: per-node attention scalars
            int idx = (rb - CNT_BLKS) * 256 + t;   // NN*2
            int n = idx >> 1, hd = idx & 1;
            float s = 0.f, dv = 0.f;
#pragma unroll
            for (int f = 0; f < 5; f++) {
                float xv = x[n * 5 + f];
                s += xv * wvec[hd * 5 + f];
                dv += xv * wvec[10 + hd * 5 + f];
            }
            as1o[idx] = s;
            ad1o[idx] = dv;
        }
        return;
    }

    // ---- protein body (R10-verified) ----
    __shared__ __align__(16) short sEmb[130 * SSTR];
    __shared__ __align__(16) short s1[132 * SSTR];

    int b = bid / NTILE;
    int tile = bid - b * NTILE;
    int t0 = tile * TL;
    int wv = t >> 6, lane = t & 63;
    int ln15 = lane & 15, quad = lane >> 4;
    int mhalf = wv & 1, nhalf = wv >> 1;

    for (int j0 = 0; j0 < 130; j0 += 64) {
        int j = j0 + (t >> 2);
        if (j < 130) {
            int c0 = (t & 3) * 16;
            int l = t0 - 3 + j;
            int id = (l >= 0 && l < LL) ? seq[b * LL + l] : -1;
            short* dst = &sEmb[j * SSTR + c0];
            if (id >= 0) {
                const short8* src = (const short8*)&Peb[id * 64 + c0];
                *(short8*)dst = src[0];
                *(short8*)(dst + 8) = src[1];
            } else {
                *(short8*)dst = (short8){0, 0, 0, 0, 0, 0, 0, 0};
                *(short8*)(dst + 8) = (short8){0, 0, 0, 0, 0, 0, 0, 0};
            }
        }
    }
    s1[(128 + (t >> 6)) * SSTR + (t & 63)] = 0;
    __syncthreads();

    {   // conv1: wave = 4 mt x 2 nt
        f32x4 acc[4][2];
#pragma unroll
        for (int mi = 0; mi < 4; mi++)
#pragma unroll
            for (int ni = 0; ni < 2; ni++) acc[mi][ni] = (f32x4){0.f, 0.f, 0.f, 0.f};
#pragma unroll
        for (int kb = 0; kb < 6; kb++) {
            int koff = kb * 32 + quad * 8;
            int kk = koff >> 6, i0 = koff & 63;
            short8 b0 = *(const short8*)&Bswz1[((kb * 4 + nhalf * 2 + 0) * 64 + lane) * 8];
            short8 b1 = *(const short8*)&Bswz1[((kb * 4 + nhalf * 2 + 1) * 64 + lane) * 8];
#pragma unroll
            for (int mi = 0; mi < 4; mi++) {
                int arow = (mhalf * 4 + mi) * 16 + ln15 + kk;
                short8 a = *(const short8*)&sEmb[arow * SSTR + i0];
                acc[mi][0] = __builtin_amdgcn_mfma_f32_16x16x32_bf16(a, b0, acc[mi][0], 0, 0, 0);
                acc[mi][1] = __builtin_amdgcn_mfma_f32_16x16x32_bf16(a, b1, acc[mi][1], 0, 0, 0);
            }
        }
#pragma unroll
        for (int mi = 0; mi < 4; mi++) {
            int mt = mhalf * 4 + mi;
#pragma unroll
            for (int ni = 0; ni < 2; ni++) {
                int col = (nhalf * 2 + ni) * 16 + ln15;
                float bias = bk1[col];
#pragma unroll
                for (int r = 0; r < 4; r++) {
                    int q = mt * 16 + quad * 4 + r;
                    int l = t0 - 2 + q;
                    float v = acc[mi][ni][r] + bias;
                    v = v > 0.f ? v : __expf(v) - 1.f;
                    s1[q * SSTR + col] = (l >= 0 && l < LL) ? f2bf(v) : (short)0;
                }
            }
        }
    }
    __syncthreads();

    // conv2: wave = 4 mt x 4 nt; B from global (L2); barrier-free K-loop
    f32x4 acc2[4][4];
#pragma unroll
    for (int mi = 0; mi < 4; mi++)
#pragma unroll
        for (int ni = 0; ni < 4; ni++) acc2[mi][ni] = (f32x4){0.f, 0.f, 0.f, 0.f};
#pragma unroll 2
    for (int kb = 0; kb < 10; kb++) {
        int koff = kb * 32 + quad * 8;
        int kk = koff >> 6, i0 = koff & 63;
        short8 a[4], bb[4];
#pragma unroll
        for (int mi = 0; mi < 4; mi++) {
            int arow = (mhalf * 4 + mi) * 16 + ln15 + kk;
            a[mi] = *(const short8*)&s1[arow * SSTR + i0];
        }
#pragma unroll
        for (int ni = 0; ni < 4; ni++)
            bb[ni] = *(const short8*)&Bswz2[((kb * 8 + nhalf * 4 + ni) * 64 + lane) * 8];
#pragma unroll
        for (int mi = 0; mi < 4; mi++)
#pragma unroll
            for (int ni = 0; ni < 4; ni++)
                acc2[mi][ni] = __builtin_amdgcn_mfma_f32_16x16x32_bf16(a[mi], bb[ni], acc2[mi][ni], 0, 0, 0);
    }

    // epilogue: masked max over raw acc, then bias+elu once (elu monotonic)
#pragma unroll
    for (int ni = 0; ni < 4; ni++) {
        int col = (nhalf * 4 + ni) * 16 + ln15;
        float mx = -1e30f;
#pragma unroll
        for (int mi = 0; mi < 4; mi++) {
#pragma unroll
            for (int r = 0; r < 4; r++) {
                int p = (mhalf * 4 + mi) * 16 + quad * 4 + r;
                if (p < TL && t0 + p < LL) mx = fmaxf(mx, acc2[mi][ni][r]);
            }
        }
        mx = fmaxf(mx, __shfl_xor(mx, 16, 64));
        mx = fmaxf(mx, __shfl_xor(mx, 32, 64));
        if (quad == 0) {
            float v = mx + bk2[col];
            v = v > 0.f ? v : __expf(v) - 1.f;
            atomicMaxFloat(&pmax[b * 128 + col], v);
        }
    }
}

// ---------------- D3: rowptr in one dispatch (redundant strided prefix; R12-verified) ----------------
__global__ void k_rowptr(const int* deg, int* rowptr) {
    __shared__ int s[256];
    __shared__ int red[4];
    int b = blockIdx.x, t = threadIdx.x, i = b * 256 + t;
    int v = deg[i];
    s[t] = v;
    __syncthreads();
    for (int o = 1; o < 256; o <<= 1) {
        int xx = (t >= o) ? s[t - o] : 0;
        __syncthreads();
        s[t] += xx;
        __syncthreads();
    }
    int excl = s[t] - v;
    int psum = 0;
    for (int k = t; k < b * 256; k += 256) psum += deg[k];
    for (int off = 32; off > 0; off >>= 1) psum += __shfl_down(psum, off, 64);
    if ((t & 63) == 0) red[t >> 6] = psum;
    __syncthreads();
    int pref = red[0] + red[1] + red[2] + red[3];
    rowptr[i] = excl + pref;
    if (i == 0) rowptr[NN] = ETOT;
}

__global__ void k_scatter(const int* ei, const int* rowptr, int* cursor, int* colidx) {
    int e = blockIdx.x * 256 + threadIdx.x;
    if (e >= ETOT) return;
    int s, d;
    if (e < NE) { s = ei[e]; d = ei[NE + e]; }
    else { s = d = e - NE; }
    int pos = atomicAdd(&cursor[d], 1);
    colidx[rowptr[d] + pos] = s;
}

// ---------------- GAT layer 1: x-space aggregation + fused W1 (no max-shift) ----------------
__global__ void k_agg2x(const int* rowptr, const int* colidx, const float* x,
                        const float* as_, const float* ad_,
                        const float* W1, const float* b1, const float* wvec,
                        unsigned int* g1b, float* as2, float* ad2) {
    __shared__ float sW[640];
    __shared__ float sb1[128];
    __shared__ float swa[256];
    int t = threadIdx.x;
    for (int i = t; i < 640; i += 256) sW[i] = W1[i];
    if (t < 128) { sb1[t] = b1[t]; swa[t] = wvec[32 + t]; swa[128 + t] = wvec[160 + t]; }
    __syncthreads();

    int d = blockIdx.x * 16 + (t >> 4);   // grid = NN/16
    int g = t & 15;
    int hd = (g < 5) ? 0 : 1;
    int f = (g < 5) ? g : g - 5;
    float adv = ad_[d * 2 + hd];
    int p0 = rowptr[d], p1 = rowptr[d + 1];
    float den = 0.f, acc = 0.f;
    if (g < 10) {
        for (int pc = p0; pc < p1; pc += 4) {
            int sarr[4]; float ev[4], xv[4];
#pragma unroll
            for (int i = 0; i < 4; i++) {
                int pp = pc + i;
                sarr[i] = colidx[pp < p1 ? pp : p1 - 1];
            }
#pragma unroll
            for (int i = 0; i < 4; i++) {
                ev[i] = as_[sarr[i] * 2 + hd];
                xv[i] = x[sarr[i] * 5 + f];
            }
#pragma unroll
            for (int i = 0; i < 4; i++) {
                if (pc + i < p1) {
                    float e = ev[i] + adv;
                    e = e >= 0.f ? e : 0.2f * e;
                    float w = __expf(e);
                    den += w;
                    acc += w * xv[i];
                }
            }
        }
    }
    float xn = acc / (den + 1e-16f);
    int gb = (t & 63) & ~15;
    int hcol = g >> 3;
    float xs[5];
#pragma unroll
    for (int f2 = 0; f2 < 5; f2++)
        xs[f2] = __shfl(xn, gb + hcol * 5 + f2, 64);
    float ps = 0.f, pd = 0.f;
    float g1v[8];
#pragma unroll
    for (int k = 0; k < 8; k++) {
        int col = g * 8 + k;
        float v = sb1[col];
#pragma unroll
        for (int f2 = 0; f2 < 5; f2++) v += xs[f2] * sW[f2 * 128 + col];
        v = v > 0.f ? v : __expf(v) - 1.f;
        g1v[k] = v;
        ps += v * swa[col];
        pd += v * swa[128 + col];
    }
    uint4 pk;
    pk.x = ((unsigned)(unsigned short)f2bf(g1v[1]) << 16) | (unsigned)(unsigned short)f2bf(g1v[0]);
    pk.y = ((unsigned)(unsigned short)f2bf(g1v[3]) << 16) | (unsigned)(unsigned short)f2bf(g1v[2]);
    pk.z = ((unsigned)(unsigned short)f2bf(g1v[5]) << 16) | (unsigned)(unsigned short)f2bf(g1v[4]);
    pk.w = ((unsigned)(unsigned short)f2bf(g1v[7]) << 16) | (unsigned)(unsigned short)f2bf(g1v[6]);
    *(uint4*)&g1b[d * 64 + g * 4] = pk;
#pragma unroll
    for (int msk = 1; msk < 16; msk <<= 1) {
        ps += __shfl_xor(ps, msk, 64);
        pd += __shfl_xor(pd, msk, 64);
    }
    if (g == 0) { as2[d] = ps; ad2[d] = pd; }
}

// ---------------- GAT layer 2 aggregation in g1-space (packed bf16; no max-shift) ----------------
__global__ void k_agg1y(const int* rowptr, const int* colidx, const unsigned int* hb,
                        const float* as_, const float* ad_, float* yacc) {
    int t = threadIdx.x;
    int d = blockIdx.x * 4 + (t >> 6);   // wave per node
    int c = t & 63;
    float adv = ad_[d];
    int p0 = rowptr[d], p1 = rowptr[d + 1];
    float den = 0.f, acc0 = 0.f, acc1 = 0.f;
    for (int pc = p0; pc < p1; pc += 4) {
        int sarr[4]; float ev[4]; unsigned int hv[4];
#pragma unroll
        for (int i = 0; i < 4; i++) {
            int pp = pc + i;
            sarr[i] = colidx[pp < p1 ? pp : p1 - 1];
        }
#pragma unroll
        for (int i = 0; i < 4; i++) {
            ev[i] = as_[sarr[i]];
            hv[i] = hb[sarr[i] * 64 + c];
        }
#pragma unroll
        for (int i = 0; i < 4; i++) {
            if (pc + i < p1) {
                float e = ev[i] + adv;
                e = e >= 0.f ? e : 0.2f * e;
                float w = __expf(e);
                den += w;
                acc0 += w * __uint_as_float(hv[i] << 16);
                acc1 += w * __uint_as_float(hv[i] & 0xFFFF0000u);
            }
        }
    }
    float inv = 1.f / (den + 1e-16f);
    ((float2*)yacc)[d * 64 + c] = (float2){acc0 * inv, acc1 * inv};
}

// ---------------- deferred layer-2 matmul: g2 = elu(yacc @ W2 + b2), split-bf16 ----------------
#define ASTR 136
__global__ __launch_bounds__(256, 2) void k_g2mm(
    const float* yacc, const short* Bh, const short* Bl, const float* b2, float* g2) {
    __shared__ __align__(16) short Ah[64 * ASTR];
    __shared__ __align__(16) short Al[64 * ASTR];
    int t = threadIdx.x;
    int m0 = blockIdx.x * 64;
    int wv = t >> 6, lane = t & 63;
    int ln15 = lane & 15, quad = lane >> 4;

    for (int i = t; i < 64 * 32; i += 256) {
        int row = i >> 5, c4 = (i & 31) * 4;
        float4 v = *(const float4*)&yacc[(m0 + row) * 128 + c4];
        short4v hi, lo;
        hi.x = f2bf(v.x); lo.x = f2bf(v.x - bf2f(hi.x));
        hi.y = f2bf(v.y); lo.y = f2bf(v.y - bf2f(hi.y));
        hi.z = f2bf(v.z); lo.z = f2bf(v.z - bf2f(hi.z));
        hi.w = f2bf(v.w); lo.w = f2bf(v.w - bf2f(hi.w));
        *(short4v*)&Ah[row * ASTR + c4] = hi;
        *(short4v*)&Al[row * ASTR + c4] = lo;
    }
    __syncthreads();

    f32x4 acc[8];
#pragma unroll
    for (int nt = 0; nt < 8; nt++) acc[nt] = (f32x4){0.f, 0.f, 0.f, 0.f};
    int arow = wv * 16 + ln15;
#pragma unroll
    for (int kb = 0; kb < 4; kb++) {
        int koff = kb * 32 + quad * 8;
        short8 a_hi = *(const short8*)&Ah[arow * ASTR + koff];
        short8 a_lo = *(const short8*)&Al[arow * ASTR + koff];
#pragma unroll
        for (int nt = 0; nt < 8; nt++) {
            short8 bh = *(const short8*)&Bh[((kb * 8 + nt) * 64 + lane) * 8];
            short8 bl = *(const short8*)&Bl[((kb * 8 + nt) * 64 + lane) * 8];
            acc[nt] = __builtin_amdgcn_mfma_f32_16x16x32_bf16(a_hi, bh, acc[nt], 0, 0, 0);
            acc[nt] = __builtin_amdgcn_mfma_f32_16x16x32_bf16(a_hi, bl, acc[nt], 0, 0, 0);
            acc[nt] = __builtin_amdgcn_mfma_f32_16x16x32_bf16(a_lo, bh, acc[nt], 0, 0, 0);
        }
    }
#pragma unroll
    for (int nt = 0; nt < 8; nt++) {
        int col = nt * 16 + ln15;
        float bias = b2[col];
#pragma unroll
        for (int r = 0; r < 4; r++) {
            float v = acc[nt][r] + bias;
            v = v > 0.f ? v : __expf(v) - 1.f;
            int n = m0 + wv * 16 + quad * 4 + r;
            g2[n * 128 + col] = v;
        }
    }
}

// ---------------- mean pool (sorted batch; 4-deep prefetch; computes cnt) ----------------
__global__ void k_pool(const float* g2, const int* batch, float* sums, float* cnt) {
    __shared__ int sb[96];
    int blk = blockIdx.x, j = threadIdx.x;
    int n0 = blk * 96;
    if (j < 96) sb[j] = batch[n0 + j];
    __syncthreads();
    float v[4];
#pragma unroll
    for (int i = 0; i < 4; i++) v[i] = g2[(n0 + i) * 128 + j];
    int cur = sb[0], runStart = 0;
    float acc = 0.f;
    for (int q0 = 0; q0 < 96; q0 += 4) {
        float nv[4] = {0.f, 0.f, 0.f, 0.f};
        if (q0 + 4 < 96) {
#pragma unroll
            for (int i = 0; i < 4; i++) nv[i] = g2[(n0 + q0 + 4 + i) * 128 + j];
        }
#pragma unroll
        for (int i = 0; i < 4; i++) {
            int q = q0 + i;
            int bb = sb[q];
            if (bb != cur) {
                atomicAdd(&sums[cur * 128 + j], acc);
                if (j == 0) atomicAdd(&cnt[cur], (float)(q - runStart));
                cur = bb; acc = 0.f; runStart = q;
            }
            acc += v[i];
        }
#pragma unroll
        for (int i = 0; i < 4; i++) v[i] = nv[i];
    }
    atomicAdd(&sums[cur * 128 + j], acc);
    if (j == 0) atomicAdd(&cnt[cur], (float)(96 - runStart));
}

// ---------------- tail v2: 512 thr, concurrent prot/drug, K-split f1/f2 (R15-verified) ----------------
__global__ __launch_bounds__(512) void k_tail(
    const float* pmax, const float* Wp, const float* bp,
    const float* sums, const float* cnt, const float* Wd, const float* bd,
    const float* Wf1, const float* bf1, const float* Wf2, const float* bf2,
    const float* Wo, const float* bo, float* out) {
    __shared__ float in2[512];
    __shared__ float part1[512];
    __shared__ float hh[128];
    __shared__ float part2[512];
    __shared__ float h2s[64];
    int g = blockIdx.x, t = threadIdx.x;

    if (t < 256) {
        float pacc = bp[t];
#pragma unroll 8
        for (int i = 0; i < 128; i++) pacc += pmax[g * 128 + i] * Wp[i * 256 + t];
        in2[256 + t] = pacc > 0.f ? pacc : 0.f;
    } else {
        int o = t - 256;
        float c = cnt[g]; c = c < 1.f ? 1.f : c;
        float inv = 1.f / c;
        float dacc = bd[o];
#pragma unroll 8
        for (int i = 0; i < 128; i++) dacc += sums[g * 128 + i] * inv * Wd[i * 256 + o];
        in2[o] = dacc > 0.f ? dacc : 0.f;
    }
    __syncthreads();

    {
        int o = t >> 2, ks = t & 3;
        float p = 0.f;
        int c0 = ks * 128;
#pragma unroll 8
        for (int cc = c0; cc < c0 + 128; cc++) p += in2[cc] * Wf1[cc * 128 + o];
        part1[t] = p;
    }
    __syncthreads();
    if (t < 128) {
        float a = bf1[t] + part1[t * 4] + part1[t * 4 + 1] + part1[t * 4 + 2] + part1[t * 4 + 3];
        hh[t] = a > 0.f ? a : 0.f;
    }
    __syncthreads();

    {
        int o = t >> 3, ks = t & 7;
        float p = 0.f;
        int c0 = ks * 16;
#pragma unroll
        for (int cc = c0; cc < c0 + 16; cc++) p += hh[cc] * Wf2[cc * 64 + o];
        part2[t] = p;
    }
    __syncthreads();
    if (t < 64) {
        float a = bf2[t];
#pragma unroll
        for (int k = 0; k < 8; k++) a += part2[t * 8 + k];
        h2s[t] = a > 0.f ? a : 0.f;
    }
    __syncthreads();

    if (t < 64) {
        float p = h2s[t] * Wo[t];
#pragma unroll
        for (int off = 32; off > 0; off >>= 1) p += __shfl_down(p, off, 64);
        if (t == 0) out[g] = p + bo[0];
    }
}

extern "C" void kernel_launch(void* const* d_in, const int* in_sizes, int n_in,
                              void* d_out, int out_size, void* d_ws, size_t ws_size,
                              hipStream_t stream) {
    (void)in_sizes; (void)n_in; (void)out_size; (void)ws_size;
    const float* x   = (const float*)d_in[0];
    const int* ei    = (const int*)d_in[1];
    const int* batch = (const int*)d_in[2];
    const int* seq   = (const int*)d_in[3];
    const float* W1  = (const float*)d_in[4];
    const float* a_s1 = (const float*)d_in[5];
    const float* a_d1 = (const float*)d_in[6];
    const float* b1  = (const float*)d_in[7];
    const float* W2  = (const float*)d_in[8];
    const float* a_s2 = (const float*)d_in[9];
    const float* a_d2 = (const float*)d_in[10];
    const float* b2  = (const float*)d_in[11];
    const float* Wd  = (const float*)d_in[12];
    const float* bd  = (const float*)d_in[13];
    const float* Pe  = (const float*)d_in[14];
    const float* K1  = (const float*)d_in[15];
    const float* bk1 = (const float*)d_in[16];
    const float* K2  = (const float*)d_in[17];
    const float* bk2 = (const float*)d_in[18];
    const float* Wp  = (const float*)d_in[19];
    const float* bp  = (const float*)d_in[20];
    const float* Wf1 = (const float*)d_in[21];
    const float* bf1 = (const float*)d_in[22];
    const float* Wf2 = (const float*)d_in[23];
    const float* bf2 = (const float*)d_in[24];
    const float* Wo  = (const float*)d_in[25];
    const float* bo  = (const float*)d_in[26];
    float* out = (float*)d_out;

    float* w = (float*)d_ws;
    float* g1bf = w; w += NN * 64;    // packed-bf16 uint[NN*64]
    float* yacc = w; w += NN * 128;
    float* g2   = w; w += NN * 128;
    float* as1  = w; w += NN * 2;
    float* ad1  = w; w += NN * 2;
    float* as2  = w; w += NN;
    float* ad2  = w; w += NN;
    float* sums = w; w += NG * 128;
    float* cnt  = w; w += NG;
    float* pmax = w; w += NB * 128;
    float* wvec = w; w += 512;
    short* Bswz1 = (short*)w; w += 192 * 64 / 2;
    short* Bswz2 = (short*)w; w += 320 * 128 / 2;
    short* Bh2  = (short*)w; w += 128 * 128 / 2;
    short* Bl2  = (short*)w; w += 128 * 128 / 2;
    short* Peb  = (short*)w; w += 22 * 64 / 2 + 8;
    int* deg    = (int*)w; w += NN;
    int* cursor = (int*)w; w += NN;
    int* rowptr = (int*)w; w += NN + 8;
    int* colidx = (int*)w; w += ETOT;

    unsigned int* g1b = (unsigned int*)g1bf;

    // D1: init + weight prep
    hipLaunchKernelGGL(k_init_prep, dim3(256 + 160), dim3(256), 0, stream,
                       deg, cursor, sums, cnt, pmax,
                       K1, K2, W2, Pe, W1, a_s1, a_d1, a_s2, a_d2,
                       Bswz1, Bswz2, Bh2, Bl2, Peb, wvec);

    // D2: protein + CSR count + as1
    hipLaunchKernelGGL(k_prot_cnt_as1, dim3(PROT_BLKS + CNT_BLKS + AS1_BLKS), dim3(256), 0, stream,
                       seq, Peb, Bswz1, bk1, Bswz2, bk2, pmax,
                       ei, deg, x, wvec, as1, ad1);

    // D3: rowptr (single dispatch)
    hipLaunchKernelGGL(k_rowptr, dim3(NN / 256), dim3(256), 0, stream, deg, rowptr);

    // D4: scatter
    hipLaunchKernelGGL(k_scatter, dim3(ETOT / 256), dim3(256), 0, stream, ei, rowptr, cursor, colidx);

    // D5: GAT layer 1 aggregation (x-space) + fused W1
    hipLaunchKernelGGL(k_agg2x, dim3(NN / 16), dim3(256), 0, stream,
                       rowptr, colidx, x, as1, ad1, W1, b1, wvec, g1b, as2, ad2);

    // D6: GAT layer 2 aggregation
    hipLaunchKernelGGL(k_agg1y, dim3(NN / 4), dim3(256), 0, stream,
                       rowptr, colidx, g1b, as2, ad2, yacc);

    // D7: deferred W2 matmul
    hipLaunchKernelGGL(k_g2mm, dim3(NN / 64), dim3(256), 0, stream,
                       yacc, Bh2, Bl2, b2, g2);

    // D8: pool
    hipLaunchKernelGGL(k_pool, dim3(NN / 96), dim3(128), 0, stream, g2, batch, sums, cnt);

    // D9: tail v2
    hipLaunchKernelGGL(k_tail, dim3(NG), dim3(512), 0, stream,
                       pmax, Wp, bp, sums, cnt, Wd, bd, Wf1, bf1, Wf2, bf2, Wo, bo, out);
}

// Round 18
// 295.443 us; speedup vs baseline: 1.0672x; 1.0480x over previous
//
#include <hip/hip_runtime.h>
#include <hip/hip_bf16.h>
#include <math.h>

#define NN 24576
#define NE 98304
#define ETOT (NE + NN)
#define NG 512
#define NB 512
#define LL 1000
#define TL 124
#define NTILE 9
#define PROT_BLKS (NB * NTILE)
#define CNT_BLKS (ETOT / 256)
#define AS1_BLKS (NN * 2 / 256)

typedef __attribute__((ext_vector_type(8))) short short8;
typedef __attribute__((ext_vector_type(4))) short short4v;
typedef __attribute__((ext_vector_type(4))) float f32x4;

__device__ inline short f2bf(float x) {
    union { __hip_bfloat16 b; short s; } u;
    u.b = __float2bfloat16(x);
    return u.s;
}

__device__ inline float bf2f(short s) {
    return __uint_as_float(((unsigned)(unsigned short)s) << 16);
}

__device__ inline void atomicMaxFloat(float* addr, float val) {
    int* ai = (int*)addr;
    int old = __float_as_int(*addr);
    while (__int_as_float(old) < val) {
        int assumed = old;
        old = atomicCAS(ai, assumed, __float_as_int(val));
        if (old == assumed) break;
    }
}

// ---------------- D1: init + weight prep (disjoint block ranges) ----------------
__global__ void k_init_prep(int* deg, int* cursor, float* sums, float* cnt, float* pmax,
                            const float* K1, const float* K2, const float* W2, const float* Pe,
                            const float* W1, const float* as1c, const float* ad1c,
                            const float* as2c, const float* ad2c,
                            short* Bswz1, short* Bswz2, short* Bh2, short* Bl2, short* Peb,
                            float* wvec) {
    int bid = blockIdx.x, t = threadIdx.x;
    if (bid < 256) {                       // init body
        int i = bid * 256 + t;
        if (i < NN) { deg[i] = 0; cursor[i] = 0; }
        if (i < NG * 128) sums[i] = 0.f;
        if (i < NG) cnt[i] = 0.f;
        if (i < NB * 128) pmax[i] = -1e30f;
        return;
    }
    int idx = (bid - 256) * 256 + t;       // prep body (160 blocks)
    if (idx < 22 * 64) Peb[idx] = f2bf(Pe[idx]);
    if (idx < 20) {             // was1 [0..9], wad1 [10..19]
        int q = idx % 10, hd = q / 5, f = q % 5;
        const float* av = (idx < 10) ? as1c : ad1c;
        float s = 0.f;
        for (int c = 0; c < 64; c++) s += W1[f * 128 + hd * 64 + c] * av[hd * 64 + c];
        wvec[idx < 10 ? q : 10 + q] = s;
    }
    if (idx >= 32 && idx < 288) {   // wa_s2 [32..159], wa_d2 [160..287]
        int q = idx - 32;
        int kk = q & 127;
        const float* av = (q < 128) ? as2c : ad2c;
        float s = 0.f;
        for (int n2 = 0; n2 < 128; n2++) s += W2[kk * 128 + n2] * av[n2];
        wvec[idx] = s;
    }
    if (idx < 192 * 64) {       // B1
        int j = idx & 7, lane = (idx >> 3) & 63, rest = idx >> 9;
        int nt = rest & 3, kb = rest >> 2;
        int k = kb * 32 + ((lane >> 4) << 3) + j;
        int n = nt * 16 + (lane & 15);
        int kk = k >> 6, i = k & 63;
        Bswz1[idx] = f2bf(K1[n * 192 + i * 3 + kk]);
    }
    if (idx < 320 * 128) {      // B2
        int j = idx & 7, lane = (idx >> 3) & 63, rest = idx >> 9;
        int nt = rest & 7, kb = rest >> 3;
        int k = kb * 32 + ((lane >> 4) << 3) + j;
        int n = nt * 16 + (lane & 15);
        int kk = k / 64, i = k % 64;
        Bswz2[idx] = f2bf(K2[n * 320 + i * 5 + kk]);
    }
    if (idx < 128 * 128) {      // W2 hi/lo
        int j = idx & 7, lane = (idx >> 3) & 63, rest = idx >> 9;
        int nt = rest & 7, kb = rest >> 3;
        int k = kb * 32 + ((lane >> 4) << 3) + j;
        int n = nt * 16 + (lane & 15);
        float v = W2[k * 128 + n];
        short hh = f2bf(v);
        Bh2[idx] = hh;
        Bl2[idx] = f2bf(v - bf2f(hh));
    }
}

// ---------------- D2: protein + CSR count + as1 (disjoint ranges; R11/R13/R15-verified) ----------------
#define SSTR 72
__global__ __launch_bounds__(256, 4) void k_prot_cnt_as1(
    const int* seq, const short* Peb, const short* Bswz1, const float* bk1,
    const short* Bswz2, const float* bk2, float* pmax,
    const int* ei, int* deg,
    const float* x, const float* wvec, float* as1o, float* ad1o) {
    int bid = blockIdx.x;
    int t = threadIdx.x;

    if (bid >= PROT_BLKS) {
        int rb = bid - PROT_BLKS;
        if (rb < CNT_BLKS) {               // CSR count
            int e = rb * 256 + t;
            int d = (e < NE) ? ei[NE + e] : e - NE;
            atomicAdd(&deg[d], 1);
        } else {                           // as1: per-node attention scalars
            int idx = (rb - CNT_BLKS) * 256 + t;   // NN*2
            int n = idx >> 1, hd = idx & 1;
            float s = 0.f, dv = 0.f;
#pragma unroll
            for (int f = 0; f < 5; f++) {
                float xv = x[n * 5 + f];
                s += xv * wvec[hd * 5 + f];
                dv += xv * wvec[10 + hd * 5 + f];
            }
            as1o[idx] = s;
            ad1o[idx] = dv;
        }
        return;
    }

    // ---- protein body (R10-verified) ----
    __shared__ __align__(16) short sEmb[130 * SSTR];
    __shared__ __align__(16) short s1[132 * SSTR];

    int b = bid / NTILE;
    int tile = bid - b * NTILE;
    int t0 = tile * TL;
    int wv = t >> 6, lane = t & 63;
    int ln15 = lane & 15, quad = lane >> 4;
    int mhalf = wv & 1, nhalf = wv >> 1;

    for (int j0 = 0; j0 < 130; j0 += 64) {
        int j = j0 + (t >> 2);
        if (j < 130) {
            int c0 = (t & 3) * 16;
            int l = t0 - 3 + j;
            int id = (l >= 0 && l < LL) ? seq[b * LL + l] : -1;
            short* dst = &sEmb[j * SSTR + c0];
            if (id >= 0) {
                const short8* src = (const short8*)&Peb[id * 64 + c0];
                *(short8*)dst = src[0];
                *(short8*)(dst + 8) = src[1];
            } else {
                *(short8*)dst = (short8){0, 0, 0, 0, 0, 0, 0, 0};
                *(short8*)(dst + 8) = (short8){0, 0, 0, 0, 0, 0, 0, 0};
            }
        }
    }
    s1[(128 + (t >> 6)) * SSTR + (t & 63)] = 0;
    __syncthreads();

    {   // conv1: wave = 4 mt x 2 nt
        f32x4 acc[4][2];
#pragma unroll
        for (int mi = 0; mi < 4; mi++)
#pragma unroll
            for (int ni = 0; ni < 2; ni++) acc[mi][ni] = (f32x4){0.f, 0.f, 0.f, 0.f};
#pragma unroll
        for (int kb = 0; kb < 6; kb++) {
            int koff = kb * 32 + quad * 8;
            int kk = koff >> 6, i0 = koff & 63;
            short8 b0 = *(const short8*)&Bswz1[((kb * 4 + nhalf * 2 + 0) * 64 + lane) * 8];
            short8 b1 = *(const short8*)&Bswz1[((kb * 4 + nhalf * 2 + 1) * 64 + lane) * 8];
#pragma unroll
            for (int mi = 0; mi < 4; mi++) {
                int arow = (mhalf * 4 + mi) * 16 + ln15 + kk;
                short8 a = *(const short8*)&sEmb[arow * SSTR + i0];
                acc[mi][0] = __builtin_amdgcn_mfma_f32_16x16x32_bf16(a, b0, acc[mi][0], 0, 0, 0);
                acc[mi][1] = __builtin_amdgcn_mfma_f32_16x16x32_bf16(a, b1, acc[mi][1], 0, 0, 0);
            }
        }
#pragma unroll
        for (int mi = 0; mi < 4; mi++) {
            int mt = mhalf * 4 + mi;
#pragma unroll
            for (int ni = 0; ni < 2; ni++) {
                int col = (nhalf * 2 + ni) * 16 + ln15;
                float bias = bk1[col];
#pragma unroll
                for (int r = 0; r < 4; r++) {
                    int q = mt * 16 + quad * 4 + r;
                    int l = t0 - 2 + q;
                    float v = acc[mi][ni][r] + bias;
                    v = v > 0.f ? v : __expf(v) - 1.f;
                    s1[q * SSTR + col] = (l >= 0 && l < LL) ? f2bf(v) : (short)0;
                }
            }
        }
    }
    __syncthreads();

    // conv2: wave = 4 mt x 4 nt; B from global (L2); barrier-free K-loop
    f32x4 acc2[4][4];
#pragma unroll
    for (int mi = 0; mi < 4; mi++)
#pragma unroll
        for (int ni = 0; ni < 4; ni++) acc2[mi][ni] = (f32x4){0.f, 0.f, 0.f, 0.f};
#pragma unroll 2
    for (int kb = 0; kb < 10; kb++) {
        int koff = kb * 32 + quad * 8;
        int kk = koff >> 6, i0 = koff & 63;
        short8 a[4], bb[4];
#pragma unroll
        for (int mi = 0; mi < 4; mi++) {
            int arow = (mhalf * 4 + mi) * 16 + ln15 + kk;
            a[mi] = *(const short8*)&s1[arow * SSTR + i0];
        }
#pragma unroll
        for (int ni = 0; ni < 4; ni++)
            bb[ni] = *(const short8*)&Bswz2[((kb * 8 + nhalf * 4 + ni) * 64 + lane) * 8];
#pragma unroll
        for (int mi = 0; mi < 4; mi++)
#pragma unroll
            for (int ni = 0; ni < 4; ni++)
                acc2[mi][ni] = __builtin_amdgcn_mfma_f32_16x16x32_bf16(a[mi], bb[ni], acc2[mi][ni], 0, 0, 0);
    }

    // epilogue: masked max over raw acc, then bias+elu once (elu monotonic)
#pragma unroll
    for (int ni = 0; ni < 4; ni++) {
        int col = (nhalf * 4 + ni) * 16 + ln15;
        float mx = -1e30f;
#pragma unroll
        for (int mi = 0; mi < 4; mi++) {
#pragma unroll
            for (int r = 0; r < 4; r++) {
                int p = (mhalf * 4 + mi) * 16 + quad * 4 + r;
                if (p < TL && t0 + p < LL) mx = fmaxf(mx, acc2[mi][ni][r]);
            }
        }
        mx = fmaxf(mx, __shfl_xor(mx, 16, 64));
        mx = fmaxf(mx, __shfl_xor(mx, 32, 64));
        if (quad == 0) {
            float v = mx + bk2[col];
            v = v > 0.f ? v : __expf(v) - 1.f;
            atomicMaxFloat(&pmax[b * 128 + col], v);
        }
    }
}

// ---------------- CSR: per-block scan ----------------
__global__ void k_scan1(const int* deg, int* excl, int* part) {
    __shared__ int s[256];
    int b = blockIdx.x, t = threadIdx.x, i = b * 256 + t;
    int v = deg[i];
    s[t] = v;
    __syncthreads();
    for (int o = 1; o < 256; o <<= 1) {
        int x = (t >= o) ? s[t - o] : 0;
        __syncthreads();
        s[t] += x;
        __syncthreads();
    }
    excl[i] = s[t] - v;
    if (t == 255) part[b] = s[t];
}

// ---------------- CSR: partial-prefix + rowptr ----------------
__global__ void k_scan23(const int* excl, const int* part, int* rowptr) {
    __shared__ int sp[96];
    __shared__ int pref;
    int b = blockIdx.x, t = threadIdx.x;   // 96 blocks x 256
    if (t < 96) sp[t] = part[t];
    __syncthreads();
    if (t == 0) {
        int run = 0;
        for (int i = 0; i < b; i++) run += sp[i];
        pref = run;
    }
    __syncthreads();
    int i = b * 256 + t;
    rowptr[i] = excl[i] + pref;
    if (i == 0) rowptr[NN] = ETOT;
}

__global__ void k_scatter(const int* ei, const int* rowptr, int* cursor, int* colidx) {
    int e = blockIdx.x * 256 + threadIdx.x;
    if (e >= ETOT) return;
    int s, d;
    if (e < NE) { s = ei[e]; d = ei[NE + e]; }
    else { s = d = e - NE; }
    int pos = atomicAdd(&cursor[d], 1);
    colidx[rowptr[d] + pos] = s;
}

// ---------------- GAT layer 1: x-space aggregation + fused W1 (no max-shift) ----------------
__global__ void k_agg2x(const int* rowptr, const int* colidx, const float* x,
                        const float* as_, const float* ad_,
                        const float* W1, const float* b1, const float* wvec,
                        unsigned int* g1b, float* as2, float* ad2) {
    __shared__ float sW[640];
    __shared__ float sb1[128];
    __shared__ float swa[256];
    int t = threadIdx.x;
    for (int i = t; i < 640; i += 256) sW[i] = W1[i];
    if (t < 128) { sb1[t] = b1[t]; swa[t] = wvec[32 + t]; swa[128 + t] = wvec[160 + t]; }
    __syncthreads();

    int d = blockIdx.x * 16 + (t >> 4);   // grid = NN/16
    int g = t & 15;
    int hd = (g < 5) ? 0 : 1;
    int f = (g < 5) ? g : g - 5;
    float adv = ad_[d * 2 + hd];
    int p0 = rowptr[d], p1 = rowptr[d + 1];
    float den = 0.f, acc = 0.f;
    if (g < 10) {
        for (int pc = p0; pc < p1; pc += 4) {
            int sarr[4]; float ev[4], xv[4];
#pragma unroll
            for (int i = 0; i < 4; i++) {
                int pp = pc + i;
                sarr[i] = colidx[pp < p1 ? pp : p1 - 1];
            }
#pragma unroll
            for (int i = 0; i < 4; i++) {
                ev[i] = as_[sarr[i] * 2 + hd];
                xv[i] = x[sarr[i] * 5 + f];
            }
#pragma unroll
            for (int i = 0; i < 4; i++) {
                if (pc + i < p1) {
                    float e = ev[i] + adv;
                    e = e >= 0.f ? e : 0.2f * e;
                    float w = __expf(e);
                    den += w;
                    acc += w * xv[i];
                }
            }
        }
    }
    float xn = acc / (den + 1e-16f);
    int gb = (t & 63) & ~15;
    int hcol = g >> 3;
    float xs[5];
#pragma unroll
    for (int f2 = 0; f2 < 5; f2++)
        xs[f2] = __shfl(xn, gb + hcol * 5 + f2, 64);
    float ps = 0.f, pd = 0.f;
    float g1v[8];
#pragma unroll
    for (int k = 0; k < 8; k++) {
        int col = g * 8 + k;
        float v = sb1[col];
#pragma unroll
        for (int f2 = 0; f2 < 5; f2++) v += xs[f2] * sW[f2 * 128 + col];
        v = v > 0.f ? v : __expf(v) - 1.f;
        g1v[k] = v;
        ps += v * swa[col];
        pd += v * swa[128 + col];
    }
    uint4 pk;
    pk.x = ((unsigned)(unsigned short)f2bf(g1v[1]) << 16) | (unsigned)(unsigned short)f2bf(g1v[0]);
    pk.y = ((unsigned)(unsigned short)f2bf(g1v[3]) << 16) | (unsigned)(unsigned short)f2bf(g1v[2]);
    pk.z = ((unsigned)(unsigned short)f2bf(g1v[5]) << 16) | (unsigned)(unsigned short)f2bf(g1v[4]);
    pk.w = ((unsigned)(unsigned short)f2bf(g1v[7]) << 16) | (unsigned)(unsigned short)f2bf(g1v[6]);
    *(uint4*)&g1b[d * 64 + g * 4] = pk;
#pragma unroll
    for (int msk = 1; msk < 16; msk <<= 1) {
        ps += __shfl_xor(ps, msk, 64);
        pd += __shfl_xor(pd, msk, 64);
    }
    if (g == 0) { as2[d] = ps; ad2[d] = pd; }
}

// ---------------- GAT layer 2 aggregation in g1-space (packed bf16; no max-shift) ----------------
__global__ void k_agg1y(const int* rowptr, const int* colidx, const unsigned int* hb,
                        const float* as_, const float* ad_, float* yacc) {
    int t = threadIdx.x;
    int d = blockIdx.x * 4 + (t >> 6);   // wave per node
    int c = t & 63;
    float adv = ad_[d];
    int p0 = rowptr[d], p1 = rowptr[d + 1];
    float den = 0.f, acc0 = 0.f, acc1 = 0.f;
    for (int pc = p0; pc < p1; pc += 4) {
        int sarr[4]; float ev[4]; unsigned int hv[4];
#pragma unroll
        for (int i = 0; i < 4; i++) {
            int pp = pc + i;
            sarr[i] = colidx[pp < p1 ? pp : p1 - 1];
        }
#pragma unroll
        for (int i = 0; i < 4; i++) {
            ev[i] = as_[sarr[i]];
            hv[i] = hb[sarr[i] * 64 + c];
        }
#pragma unroll
        for (int i = 0; i < 4; i++) {
            if (pc + i < p1) {
                float e = ev[i] + adv;
                e = e >= 0.f ? e : 0.2f * e;
                float w = __expf(e);
                den += w;
                acc0 += w * __uint_as_float(hv[i] << 16);
                acc1 += w * __uint_as_float(hv[i] & 0xFFFF0000u);
            }
        }
    }
    float inv = 1.f / (den + 1e-16f);
    ((float2*)yacc)[d * 64 + c] = (float2){acc0 * inv, acc1 * inv};
}

// ---------------- deferred layer-2 matmul: g2 = elu(yacc @ W2 + b2), split-bf16 ----------------
#define ASTR 136
__global__ __launch_bounds__(256, 2) void k_g2mm(
    const float* yacc, const short* Bh, const short* Bl, const float* b2, float* g2) {
    __shared__ __align__(16) short Ah[64 * ASTR];
    __shared__ __align__(16) short Al[64 * ASTR];
    int t = threadIdx.x;
    int m0 = blockIdx.x * 64;
    int wv = t >> 6, lane = t & 63;
    int ln15 = lane & 15, quad = lane >> 4;

    for (int i = t; i < 64 * 32; i += 256) {
        int row = i >> 5, c4 = (i & 31) * 4;
        float4 v = *(const float4*)&yacc[(m0 + row) * 128 + c4];
        short4v hi, lo;
        hi.x = f2bf(v.x); lo.x = f2bf(v.x - bf2f(hi.x));
        hi.y = f2bf(v.y); lo.y = f2bf(v.y - bf2f(hi.y));
        hi.z = f2bf(v.z); lo.z = f2bf(v.z - bf2f(hi.z));
        hi.w = f2bf(v.w); lo.w = f2bf(v.w - bf2f(hi.w));
        *(short4v*)&Ah[row * ASTR + c4] = hi;
        *(short4v*)&Al[row * ASTR + c4] = lo;
    }
    __syncthreads();

    f32x4 acc[8];
#pragma unroll
    for (int nt = 0; nt < 8; nt++) acc[nt] = (f32x4){0.f, 0.f, 0.f, 0.f};
    int arow = wv * 16 + ln15;
#pragma unroll
    for (int kb = 0; kb < 4; kb++) {
        int koff = kb * 32 + quad * 8;
        short8 a_hi = *(const short8*)&Ah[arow * ASTR + koff];
        short8 a_lo = *(const short8*)&Al[arow * ASTR + koff];
#pragma unroll
        for (int nt = 0; nt < 8; nt++) {
            short8 bh = *(const short8*)&Bh[((kb * 8 + nt) * 64 + lane) * 8];
            short8 bl = *(const short8*)&Bl[((kb * 8 + nt) * 64 + lane) * 8];
            acc[nt] = __builtin_amdgcn_mfma_f32_16x16x32_bf16(a_hi, bh, acc[nt], 0, 0, 0);
            acc[nt] = __builtin_amdgcn_mfma_f32_16x16x32_bf16(a_hi, bl, acc[nt], 0, 0, 0);
            acc[nt] = __builtin_amdgcn_mfma_f32_16x16x32_bf16(a_lo, bh, acc[nt], 0, 0, 0);
        }
    }
#pragma unroll
    for (int nt = 0; nt < 8; nt++) {
        int col = nt * 16 + ln15;
        float bias = b2[col];
#pragma unroll
        for (int r = 0; r < 4; r++) {
            float v = acc[nt][r] + bias;
            v = v > 0.f ? v : __expf(v) - 1.f;
            int n = m0 + wv * 16 + quad * 4 + r;
            g2[n * 128 + col] = v;
        }
    }
}

// ---------------- mean pool (sorted batch; 4-deep prefetch; computes cnt) ----------------
__global__ void k_pool(const float* g2, const int* batch, float* sums, float* cnt) {
    __shared__ int sb[96];
    int blk = blockIdx.x, j = threadIdx.x;
    int n0 = blk * 96;
    if (j < 96) sb[j] = batch[n0 + j];
    __syncthreads();
    float v[4];
#pragma unroll
    for (int i = 0; i < 4; i++) v[i] = g2[(n0 + i) * 128 + j];
    int cur = sb[0], runStart = 0;
    float acc = 0.f;
    for (int q0 = 0; q0 < 96; q0 += 4) {
        float nv[4] = {0.f, 0.f, 0.f, 0.f};
        if (q0 + 4 < 96) {
#pragma unroll
            for (int i = 0; i < 4; i++) nv[i] = g2[(n0 + q0 + 4 + i) * 128 + j];
        }
#pragma unroll
        for (int i = 0; i < 4; i++) {
            int q = q0 + i;
            int bb = sb[q];
            if (bb != cur) {
                atomicAdd(&sums[cur * 128 + j], acc);
                if (j == 0) atomicAdd(&cnt[cur], (float)(q - runStart));
                cur = bb; acc = 0.f; runStart = q;
            }
            acc += v[i];
        }
#pragma unroll
        for (int i = 0; i < 4; i++) v[i] = nv[i];
    }
    atomicAdd(&sums[cur * 128 + j], acc);
    if (j == 0) atomicAdd(&cnt[cur], (float)(96 - runStart));
}

// ---------------- tail v2: 512 thr, concurrent prot/drug, K-split f1/f2 (R15-verified) ----------------
__global__ __launch_bounds__(512) void k_tail(
    const float* pmax, const float* Wp, const float* bp,
    const float* sums, const float* cnt, const float* Wd, const float* bd,
    const float* Wf1, const float* bf1, const float* Wf2, const float* bf2,
    const float* Wo, const float* bo, float* out) {
    __shared__ float in2[512];
    __shared__ float part1[512];
    __shared__ float hh[128];
    __shared__ float part2[512];
    __shared__ float h2s[64];
    int g = blockIdx.x, t = threadIdx.x;

    if (t < 256) {
        float pacc = bp[t];
#pragma unroll 8
        for (int i = 0; i < 128; i++) pacc += pmax[g * 128 + i] * Wp[i * 256 + t];
        in2[256 + t] = pacc > 0.f ? pacc : 0.f;
    } else {
        int o = t - 256;
        float c = cnt[g]; c = c < 1.f ? 1.f : c;
        float inv = 1.f / c;
        float dacc = bd[o];
#pragma unroll 8
        for (int i = 0; i < 128; i++) dacc += sums[g * 128 + i] * inv * Wd[i * 256 + o];
        in2[o] = dacc > 0.f ? dacc : 0.f;
    }
    __syncthreads();

    {
        int o = t >> 2, ks = t & 3;
        float p = 0.f;
        int c0 = ks * 128;
#pragma unroll 8
        for (int cc = c0; cc < c0 + 128; cc++) p += in2[cc] * Wf1[cc * 128 + o];
        part1[t] = p;
    }
    __syncthreads();
    if (t < 128) {
        float a = bf1[t] + part1[t * 4] + part1[t * 4 + 1] + part1[t * 4 + 2] + part1[t * 4 + 3];
        hh[t] = a > 0.f ? a : 0.f;
    }
    __syncthreads();

    {
        int o = t >> 3, ks = t & 7;
        float p = 0.f;
        int c0 = ks * 16;
#pragma unroll
        for (int cc = c0; cc < c0 + 16; cc++) p += hh[cc] * Wf2[cc * 64 + o];
        part2[t] = p;
    }
    __syncthreads();
    if (t < 64) {
        float a = bf2[t];
#pragma unroll
        for (int k = 0; k < 8; k++) a += part2[t * 8 + k];
        h2s[t] = a > 0.f ? a : 0.f;
    }
    __syncthreads();

    if (t < 64) {
        float p = h2s[t] * Wo[t];
#pragma unroll
        for (int off = 32; off > 0; off >>= 1) p += __shfl_down(p, off, 64);
        if (t == 0) out[g] = p + bo[0];
    }
}

extern "C" void kernel_launch(void* const* d_in, const int* in_sizes, int n_in,
                              void* d_out, int out_size, void* d_ws, size_t ws_size,
                              hipStream_t stream) {
    (void)in_sizes; (void)n_in; (void)out_size; (void)ws_size;
    const float* x   = (const float*)d_in[0];
    const int* ei    = (const int*)d_in[1];
    const int* batch = (const int*)d_in[2];
    const int* seq   = (const int*)d_in[3];
    const float* W1  = (const float*)d_in[4];
    const float* a_s1 = (const float*)d_in[5];
    const float* a_d1 = (const float*)d_in[6];
    const float* b1  = (const float*)d_in[7];
    const float* W2  = (const float*)d_in[8];
    const float* a_s2 = (const float*)d_in[9];
    const float* a_d2 = (const float*)d_in[10];
    const float* b2  = (const float*)d_in[11];
    const float* Wd  = (const float*)d_in[12];
    const float* bd  = (const float*)d_in[13];
    const float* Pe  = (const float*)d_in[14];
    const float* K1  = (const float*)d_in[15];
    const float* bk1 = (const float*)d_in[16];
    const float* K2  = (const float*)d_in[17];
    const float* bk2 = (const float*)d_in[18];
    const float* Wp  = (const float*)d_in[19];
    const float* bp  = (const float*)d_in[20];
    const float* Wf1 = (const float*)d_in[21];
    const float* bf1 = (const float*)d_in[22];
    const float* Wf2 = (const float*)d_in[23];
    const float* bf2 = (const float*)d_in[24];
    const float* Wo  = (const float*)d_in[25];
    const float* bo  = (const float*)d_in[26];
    float* out = (float*)d_out;

    float* w = (float*)d_ws;
    float* g1bf = w; w += NN * 64;    // packed-bf16 uint[NN*64]
    float* yacc = w; w += NN * 128;
    float* g2   = w; w += NN * 128;
    float* as1  = w; w += NN * 2;
    float* ad1  = w; w += NN * 2;
    float* as2  = w; w += NN;
    float* ad2  = w; w += NN;
    float* sums = w; w += NG * 128;
    float* cnt  = w; w += NG;
    float* pmax = w; w += NB * 128;
    float* wvec = w; w += 512;
    short* Bswz1 = (short*)w; w += 192 * 64 / 2;
    short* Bswz2 = (short*)w; w += 320 * 128 / 2;
    short* Bh2  = (short*)w; w += 128 * 128 / 2;
    short* Bl2  = (short*)w; w += 128 * 128 / 2;
    short* Peb  = (short*)w; w += 22 * 64 / 2 + 8;
    int* deg    = (int*)w; w += NN;
    int* cursor = (int*)w; w += NN;
    int* excl   = (int*)w; w += NN;
    int* part   = (int*)w; w += 128;
    int* rowptr = (int*)w; w += NN + 8;
    int* colidx = (int*)w; w += ETOT;

    unsigned int* g1b = (unsigned int*)g1bf;

    // D1: init + weight prep
    hipLaunchKernelGGL(k_init_prep, dim3(256 + 160), dim3(256), 0, stream,
                       deg, cursor, sums, cnt, pmax,
                       K1, K2, W2, Pe, W1, a_s1, a_d1, a_s2, a_d2,
                       Bswz1, Bswz2, Bh2, Bl2, Peb, wvec);

    // D2: protein + CSR count + as1
    hipLaunchKernelGGL(k_prot_cnt_as1, dim3(PROT_BLKS + CNT_BLKS + AS1_BLKS), dim3(256), 0, stream,
                       seq, Peb, Bswz1, bk1, Bswz2, bk2, pmax,
                       ei, deg, x, wvec, as1, ad1);

    // D3-D5: CSR scan + scatter
    hipLaunchKernelGGL(k_scan1, dim3(NN / 256), dim3(256), 0, stream, deg, excl, part);
    hipLaunchKernelGGL(k_scan23, dim3(NN / 256), dim3(256), 0, stream, excl, part, rowptr);
    hipLaunchKernelGGL(k_scatter, dim3(ETOT / 256), dim3(256), 0, stream, ei, rowptr, cursor, colidx);

    // D6: GAT layer 1 aggregation (x-space) + fused W1
    hipLaunchKernelGGL(k_agg2x, dim3(NN / 16), dim3(256), 0, stream,
                       rowptr, colidx, x, as1, ad1, W1, b1, wvec, g1b, as2, ad2);

    // D7: GAT layer 2 aggregation
    hipLaunchKernelGGL(k_agg1y, dim3(NN / 4), dim3(256), 0, stream,
                       rowptr, colidx, g1b, as2, ad2, yacc);

    // D8: deferred W2 matmul
    hipLaunchKernelGGL(k_g2mm, dim3(NN / 64), dim3(256), 0, stream,
                       yacc, Bh2, Bl2, b2, g2);

    // D9: pool
    hipLaunchKernelGGL(k_pool, dim3(NN / 96), dim3(128), 0, stream, g2, batch, sums, cnt);

    // D10: tail v2
    hipLaunchKernelGGL(k_tail, dim3(NG), dim3(512), 0, stream,
                       pmax, Wp, bp, sums, cnt, Wd, bd, Wf1, bf1, Wf2, bf2, Wo, bo, out);
}